// Round 1
// baseline (1800.601 us; speedup 1.0000x reference)
//
#include <hip/hip_runtime.h>
#include <math.h>

#define BB 2
#define CC 2048
#define DD 1024
#define HH 16
#define DHH 64
#define HALF 32

// ---------------- RoPE cos/sin table ----------------
// theta_t = 10000^(-2*(t-1)/64)  (note the (t-1), faithful to reference)
// ang = m * theta computed in f32 (matches reference's f32 multiply)
__global__ __launch_bounds__(256) void rope_table_k(float* __restrict__ ct, float* __restrict__ st) {
    int idx = blockIdx.x * 256 + threadIdx.x;
    if (idx >= CC * HALF) return;
    int m = idx >> 5;
    int t = idx & 31;
    double theta_d = pow(10000.0, -2.0 * ((double)t - 1.0) / 64.0);
    float theta = (float)theta_d;
    float ang = (float)m * theta;
    ct[idx] = cosf(ang);
    st[idx] = sinf(ang);
}

// ---------------- QKV GEMM ----------------
// qkv[m,n] = sum_k x[m,k] * w[n,k];  scatter into q/k/v laid out [B,H,C,dh]
__global__ __launch_bounds__(256) void qkv_gemm_k(const float* __restrict__ x, const float* __restrict__ w,
                                                  float* __restrict__ q, float* __restrict__ k,
                                                  float* __restrict__ v) {
    __shared__ float As[32][132];  // [kk][m], pad 132 (mult of 4 for float4 align)
    __shared__ float Bs[32][132];  // [kk][n]
    const int m0 = blockIdx.x * 128;
    const int n0 = blockIdx.y * 128;
    const int tid = threadIdx.x;
    const int tx = tid & 15;
    const int ty = tid >> 4;
    float acc[8][8];
#pragma unroll
    for (int i = 0; i < 8; i++)
#pragma unroll
        for (int j = 0; j < 8; j++) acc[i][j] = 0.0f;

    for (int k0 = 0; k0 < 1024; k0 += 32) {
#pragma unroll
        for (int rep = 0; rep < 4; rep++) {
            int idx = rep * 256 + tid;
            int row = idx >> 3;   // 0..127
            int kq  = idx & 7;    // 0..7 (float4 along k)
            float4 xa = *(const float4*)(x + (size_t)(m0 + row) * 1024 + k0 + kq * 4);
            As[kq*4+0][row] = xa.x; As[kq*4+1][row] = xa.y;
            As[kq*4+2][row] = xa.z; As[kq*4+3][row] = xa.w;
            float4 wb = *(const float4*)(w + (size_t)(n0 + row) * 1024 + k0 + kq * 4);
            Bs[kq*4+0][row] = wb.x; Bs[kq*4+1][row] = wb.y;
            Bs[kq*4+2][row] = wb.z; Bs[kq*4+3][row] = wb.w;
        }
        __syncthreads();
#pragma unroll 4
        for (int kk = 0; kk < 32; kk++) {
            float a[8], b[8];
            *(float4*)(a + 0) = *(const float4*)&As[kk][ty * 8];
            *(float4*)(a + 4) = *(const float4*)&As[kk][ty * 8 + 4];
            *(float4*)(b + 0) = *(const float4*)&Bs[kk][tx * 4];
            *(float4*)(b + 4) = *(const float4*)&Bs[kk][64 + tx * 4];
#pragma unroll
            for (int i = 0; i < 8; i++)
#pragma unroll
                for (int j = 0; j < 8; j++) acc[i][j] += a[i] * b[j];
        }
        __syncthreads();
    }
    // write out, scatter to q/k/v in [B,H,C,dh]
#pragma unroll
    for (int i = 0; i < 8; i++) {
        int m = m0 + ty * 8 + i;
        int bb = m >> 11;
        int cpos = m & 2047;
#pragma unroll
        for (int g = 0; g < 2; g++) {
            int n = n0 + g * 64 + tx * 4;
            int part = n >> 10;
            int d = n & 1023;
            int h = d >> 6;
            int t = d & 63;
            float* dst = (part == 0) ? q : ((part == 1) ? k : v);
            float4 val;
            val.x = acc[i][g*4+0]; val.y = acc[i][g*4+1];
            val.z = acc[i][g*4+2]; val.w = acc[i][g*4+3];
            *(float4*)(dst + (((size_t)bb * HH + h) * CC + cpos) * DHH + t) = val;
        }
    }
}

// ---------------- Fused attention ----------------
// Per block: 64 queries of one (b,h). Loop all k-tiles for denominator (full, un-rotated),
// numerator+PV only on causal tiles (rotated). Rotation done in-LDS from the table.
__global__ __launch_bounds__(256) void attn_k(const float* __restrict__ qg, const float* __restrict__ kg,
                                              const float* __restrict__ vg, const float* __restrict__ ct,
                                              const float* __restrict__ st, float* __restrict__ y) {
    __shared__ float Qs[64][68];
    __shared__ float Qr[64][68];
    __shared__ float Ks[64][68];
    __shared__ float Kr[64][68];
    __shared__ float Vs[64][68];
    __shared__ float Ps[64][68];
    __shared__ float dsum[64][17];

    const int bh = blockIdx.y;
    const int b = bh >> 4;
    const int h = bh & 15;
    const int q0 = blockIdx.x * 64;
    const float* qb = qg + (size_t)bh * CC * DHH;
    const float* kb = kg + (size_t)bh * CC * DHH;
    const float* vb = vg + (size_t)bh * CC * DHH;
    const int tid = threadIdx.x;
    const int tx = tid & 15;
    const int ty = tid >> 4;

    // load Q tile
#pragma unroll
    for (int rep = 0; rep < 4; rep++) {
        int idx = rep * 256 + tid;
        int row = idx >> 4;
        int c4 = idx & 15;
        *(float4*)&Qs[row][c4 * 4] = *(const float4*)(qb + (size_t)(q0 + row) * DHH + c4 * 4);
    }
    __syncthreads();
    // rotate Q (q_rot[2t] = e*c + o*s ; q_rot[2t+1] = o*c - e*s)
#pragma unroll
    for (int rep = 0; rep < 8; rep++) {
        int idx = rep * 256 + tid;
        int row = idx >> 5;
        int t = idx & 31;
        float c = ct[(q0 + row) * 32 + t];
        float s = st[(q0 + row) * 32 + t];
        float e = Qs[row][2 * t];
        float o = Qs[row][2 * t + 1];
        Qr[row][2 * t]     = e * c + o * s;
        Qr[row][2 * t + 1] = o * c - e * s;
    }

    float yacc[4][4];
    float dacc[4];
#pragma unroll
    for (int i = 0; i < 4; i++) {
        dacc[i] = 0.0f;
#pragma unroll
        for (int j = 0; j < 4; j++) yacc[i][j] = 0.0f;
    }

    for (int kt = 0; kt < CC / 64; kt++) {
        const int k0 = kt * 64;
        const bool need_num = (k0 <= q0 + 63);
        __syncthreads();  // previous tile's compute done
        // stage K (always, for denominator); V only when tile intersects causal region
#pragma unroll
        for (int rep = 0; rep < 4; rep++) {
            int idx = rep * 256 + tid;
            int row = idx >> 4;
            int c4 = idx & 15;
            *(float4*)&Ks[row][c4 * 4] = *(const float4*)(kb + (size_t)(k0 + row) * DHH + c4 * 4);
            if (need_num)
                *(float4*)&Vs[row][c4 * 4] = *(const float4*)(vb + (size_t)(k0 + row) * DHH + c4 * 4);
        }
        __syncthreads();
        if (need_num) {
#pragma unroll
            for (int rep = 0; rep < 8; rep++) {
                int idx = rep * 256 + tid;
                int row = idx >> 5;
                int t = idx & 31;
                float c = ct[(k0 + row) * 32 + t];
                float s = st[(k0 + row) * 32 + t];
                float e = Ks[row][2 * t];
                float o = Ks[row][2 * t + 1];
                Kr[row][2 * t]     = e * c + o * s;
                Kr[row][2 * t + 1] = o * c - e * s;
            }
            __syncthreads();
        }

        float sden[4][4];
        float snum[4][4];
#pragma unroll
        for (int i = 0; i < 4; i++)
#pragma unroll
            for (int j = 0; j < 4; j++) { sden[i][j] = 0.0f; snum[i][j] = 0.0f; }

        if (need_num) {
#pragma unroll 4
            for (int d4 = 0; d4 < 16; d4++) {
                float4 qv[4], kv[4], qrv[4], krv[4];
#pragma unroll
                for (int i = 0; i < 4; i++) {
                    qv[i]  = *(const float4*)&Qs[ty + 16 * i][d4 * 4];
                    qrv[i] = *(const float4*)&Qr[ty + 16 * i][d4 * 4];
                }
#pragma unroll
                for (int j = 0; j < 4; j++) {
                    kv[j]  = *(const float4*)&Ks[tx + 16 * j][d4 * 4];
                    krv[j] = *(const float4*)&Kr[tx + 16 * j][d4 * 4];
                }
#pragma unroll
                for (int i = 0; i < 4; i++)
#pragma unroll
                    for (int j = 0; j < 4; j++) {
                        sden[i][j] += qv[i].x * kv[j].x + qv[i].y * kv[j].y
                                    + qv[i].z * kv[j].z + qv[i].w * kv[j].w;
                        snum[i][j] += qrv[i].x * krv[j].x + qrv[i].y * krv[j].y
                                    + qrv[i].z * krv[j].z + qrv[i].w * krv[j].w;
                    }
            }
        } else {
#pragma unroll 4
            for (int d4 = 0; d4 < 16; d4++) {
                float4 qv[4], kv[4];
#pragma unroll
                for (int i = 0; i < 4; i++) qv[i] = *(const float4*)&Qs[ty + 16 * i][d4 * 4];
#pragma unroll
                for (int j = 0; j < 4; j++) kv[j] = *(const float4*)&Ks[tx + 16 * j][d4 * 4];
#pragma unroll
                for (int i = 0; i < 4; i++)
#pragma unroll
                    for (int j = 0; j < 4; j++)
                        sden[i][j] += qv[i].x * kv[j].x + qv[i].y * kv[j].y
                                    + qv[i].z * kv[j].z + qv[i].w * kv[j].w;
            }
        }

        // denominator accumulate (ALL keys, un-rotated, no causal mask — per reference)
#pragma unroll
        for (int i = 0; i < 4; i++)
#pragma unroll
            for (int j = 0; j < 4; j++)
                dacc[i] += __expf(sden[i][j] * 0.125f);

        if (need_num) {
#pragma unroll
            for (int i = 0; i < 4; i++) {
                int qpos = q0 + ty + 16 * i;
#pragma unroll
                for (int j = 0; j < 4; j++) {
                    int kpos = k0 + tx + 16 * j;
                    float p = (kpos <= qpos) ? __expf(snum[i][j] * 0.125f) : 0.0f;
                    Ps[ty + 16 * i][tx + 16 * j] = p;
                }
            }
            __syncthreads();
            // PV accumulate
#pragma unroll 4
            for (int k4 = 0; k4 < 16; k4++) {
                float4 pv[4], vv[4];
#pragma unroll
                for (int i = 0; i < 4; i++) pv[i] = *(const float4*)&Ps[ty + 16 * i][k4 * 4];
#pragma unroll
                for (int kk = 0; kk < 4; kk++) vv[kk] = *(const float4*)&Vs[k4 * 4 + kk][tx * 4];
#pragma unroll
                for (int i = 0; i < 4; i++) {
                    float p0 = pv[i].x, p1 = pv[i].y, p2 = pv[i].z, p3 = pv[i].w;
                    yacc[i][0] += p0 * vv[0].x + p1 * vv[1].x + p2 * vv[2].x + p3 * vv[3].x;
                    yacc[i][1] += p0 * vv[0].y + p1 * vv[1].y + p2 * vv[2].y + p3 * vv[3].y;
                    yacc[i][2] += p0 * vv[0].z + p1 * vv[1].z + p2 * vv[2].z + p3 * vv[3].z;
                    yacc[i][3] += p0 * vv[0].w + p1 * vv[1].w + p2 * vv[2].w + p3 * vv[3].w;
                }
            }
        }
    }

    // reduce denominator across the 16 tx lanes, divide, write y [B,C,D]
    __syncthreads();
#pragma unroll
    for (int i = 0; i < 4; i++) dsum[ty + 16 * i][tx] = dacc[i];
    __syncthreads();
#pragma unroll
    for (int i = 0; i < 4; i++) {
        int row = ty + 16 * i;
        float den = 0.0f;
#pragma unroll
        for (int t2 = 0; t2 < 16; t2++) den += dsum[row][t2];
        float inv = 1.0f / den;
        float4 o4;
        o4.x = yacc[i][0] * inv;
        o4.y = yacc[i][1] * inv;
        o4.z = yacc[i][2] * inv;
        o4.w = yacc[i][3] * inv;
        *(float4*)(y + ((size_t)b * CC + q0 + row) * DD + h * DHH + tx * 4) = o4;
    }
}

// ---------------- Output projection ----------------
// out[m,n] = sum_k y[m,k] * w[n,k] + bias[n]
__global__ __launch_bounds__(256) void out_proj_k(const float* __restrict__ yin, const float* __restrict__ w,
                                                  const float* __restrict__ bias, float* __restrict__ out) {
    __shared__ float As[32][132];
    __shared__ float Bs[32][132];
    const int m0 = blockIdx.x * 128;
    const int n0 = blockIdx.y * 128;
    const int tid = threadIdx.x;
    const int tx = tid & 15;
    const int ty = tid >> 4;
    float acc[8][8];
#pragma unroll
    for (int i = 0; i < 8; i++)
#pragma unroll
        for (int j = 0; j < 8; j++) acc[i][j] = 0.0f;

    for (int k0 = 0; k0 < 1024; k0 += 32) {
#pragma unroll
        for (int rep = 0; rep < 4; rep++) {
            int idx = rep * 256 + tid;
            int row = idx >> 3;
            int kq  = idx & 7;
            float4 xa = *(const float4*)(yin + (size_t)(m0 + row) * 1024 + k0 + kq * 4);
            As[kq*4+0][row] = xa.x; As[kq*4+1][row] = xa.y;
            As[kq*4+2][row] = xa.z; As[kq*4+3][row] = xa.w;
            float4 wb = *(const float4*)(w + (size_t)(n0 + row) * 1024 + k0 + kq * 4);
            Bs[kq*4+0][row] = wb.x; Bs[kq*4+1][row] = wb.y;
            Bs[kq*4+2][row] = wb.z; Bs[kq*4+3][row] = wb.w;
        }
        __syncthreads();
#pragma unroll 4
        for (int kk = 0; kk < 32; kk++) {
            float a[8], b[8];
            *(float4*)(a + 0) = *(const float4*)&As[kk][ty * 8];
            *(float4*)(a + 4) = *(const float4*)&As[kk][ty * 8 + 4];
            *(float4*)(b + 0) = *(const float4*)&Bs[kk][tx * 4];
            *(float4*)(b + 4) = *(const float4*)&Bs[kk][64 + tx * 4];
#pragma unroll
            for (int i = 0; i < 8; i++)
#pragma unroll
                for (int j = 0; j < 8; j++) acc[i][j] += a[i] * b[j];
        }
        __syncthreads();
    }
#pragma unroll
    for (int i = 0; i < 8; i++) {
        int m = m0 + ty * 8 + i;
#pragma unroll
        for (int g = 0; g < 2; g++) {
            int n = n0 + g * 64 + tx * 4;
            float4 bv = *(const float4*)(bias + n);
            float4 val;
            val.x = acc[i][g*4+0] + bv.x; val.y = acc[i][g*4+1] + bv.y;
            val.z = acc[i][g*4+2] + bv.z; val.w = acc[i][g*4+3] + bv.w;
            *(float4*)(out + (size_t)m * 1024 + n) = val;
        }
    }
}

extern "C" void kernel_launch(void* const* d_in, const int* in_sizes, int n_in,
                              void* d_out, int out_size, void* d_ws, size_t ws_size,
                              hipStream_t stream) {
    (void)in_sizes; (void)n_in; (void)out_size; (void)ws_size;
    const float* x     = (const float*)d_in[0];
    const float* w_qkv = (const float*)d_in[1];
    const float* w_out = (const float*)d_in[2];
    const float* b_out = (const float*)d_in[3];
    float* out = (float*)d_out;
    float* ws  = (float*)d_ws;

    const size_t TEN = (size_t)BB * HH * CC * DHH;  // 4,194,304 floats
    float* qb = ws;
    float* kb = qb + TEN;
    float* vb = kb + TEN;
    float* yb = vb + TEN;
    float* ct = yb + TEN;
    float* st = ct + (size_t)CC * HALF;
    // total ws use: 4*TEN + 2*65536 floats = 67.6 MB

    rope_table_k<<<dim3((CC * HALF) / 256), dim3(256), 0, stream>>>(ct, st);
    qkv_gemm_k<<<dim3(32, 24), dim3(256), 0, stream>>>(x, w_qkv, qb, kb, vb);
    attn_k<<<dim3(32, 32), dim3(256), 0, stream>>>(qb, kb, vb, ct, st, yb);
    out_proj_k<<<dim3(32, 8), dim3(256), 0, stream>>>(yb, w_out, b_out, out);
}

// Round 2
// 197.149 us; speedup vs baseline: 9.1332x; 9.1332x over previous
//
#include <hip/hip_runtime.h>
#include <math.h>
#include <stdint.h>

#define BB 2
#define CC 2048
#define DD 1024
#define HH 16
#define DHH 64
#define HALF 32

typedef __attribute__((ext_vector_type(8))) short bf16x8;
typedef __attribute__((ext_vector_type(4))) float f32x4;

__device__ __forceinline__ ushort f2bf(float f) {
    uint32_t u = __builtin_bit_cast(uint32_t, f);
    u = (u + 0x7FFFu + ((u >> 16) & 1u)) >> 16;
    return (ushort)u;
}
__device__ __forceinline__ float bf2f(ushort u) {
    return __builtin_bit_cast(float, ((uint32_t)u) << 16);
}

// ---------------- fp32 -> bf16 cast (8 elems/thread) ----------------
__global__ __launch_bounds__(256) void cast_bf16_k(const float* __restrict__ src,
                                                   ushort* __restrict__ dst, int n8) {
    int id = blockIdx.x * 256 + threadIdx.x;
    if (id >= n8) return;
    float4 a = *reinterpret_cast<const float4*>(src + (size_t)id * 8);
    float4 b = *reinterpret_cast<const float4*>(src + (size_t)id * 8 + 4);
    bf16x8 o;
    o[0] = (short)f2bf(a.x); o[1] = (short)f2bf(a.y);
    o[2] = (short)f2bf(a.z); o[3] = (short)f2bf(a.w);
    o[4] = (short)f2bf(b.x); o[5] = (short)f2bf(b.y);
    o[6] = (short)f2bf(b.z); o[7] = (short)f2bf(b.w);
    *reinterpret_cast<bf16x8*>(dst + (size_t)id * 8) = o;
}

// ---------------- RoPE cos/sin table (fp32) ----------------
__global__ __launch_bounds__(256) void rope_table_k(float* __restrict__ ct, float* __restrict__ st) {
    int idx = blockIdx.x * 256 + threadIdx.x;
    if (idx >= CC * HALF) return;
    int m = idx >> 5;
    int t = idx & 31;
    double theta_d = pow(10000.0, -2.0 * ((double)t - 1.0) / 64.0);
    float theta = (float)theta_d;
    float ang = (float)m * theta;
    ct[idx] = cosf(ang);
    st[idx] = sinf(ang);
}

// ---------------- QKV GEMM (bf16 MFMA) ----------------
// C[m][n] = sum_k x[m][k]*w[n][k]; scatter n -> q/k/v bf16 in [B,H,C,64]
__global__ __launch_bounds__(256) void qkv_gemm_mfma_k(const ushort* __restrict__ xb,
                                                       const ushort* __restrict__ wqb,
                                                       ushort* __restrict__ q,
                                                       ushort* __restrict__ k,
                                                       ushort* __restrict__ v) {
    __shared__ ushort Al[128][72];
    __shared__ ushort Bl[128][72];
    const int tid = threadIdx.x;
    const int w = tid >> 6, l = tid & 63;
    const int l15 = l & 15, lg = l >> 4;
    const int wr = w >> 1, wc = w & 1;
    const int m0 = blockIdx.x * 128, n0 = blockIdx.y * 128;

    f32x4 acc[4][4];
#pragma unroll
    for (int i = 0; i < 4; i++)
#pragma unroll
        for (int j = 0; j < 4; j++) acc[i][j] = (f32x4){0.f, 0.f, 0.f, 0.f};

    for (int k0 = 0; k0 < 1024; k0 += 64) {
        __syncthreads();
#pragma unroll
        for (int rep = 0; rep < 4; rep++) {
            int id = rep * 256 + tid;
            int row = id >> 3, oct = id & 7;
            *reinterpret_cast<bf16x8*>(&Al[row][oct * 8]) =
                *reinterpret_cast<const bf16x8*>(xb + (size_t)(m0 + row) * 1024 + k0 + oct * 8);
            *reinterpret_cast<bf16x8*>(&Bl[row][oct * 8]) =
                *reinterpret_cast<const bf16x8*>(wqb + (size_t)(n0 + row) * 1024 + k0 + oct * 8);
        }
        __syncthreads();
#pragma unroll
        for (int kk = 0; kk < 2; kk++) {
            bf16x8 a[4], b[4];
#pragma unroll
            for (int mt = 0; mt < 4; mt++)
                a[mt] = *reinterpret_cast<const bf16x8*>(&Al[wr * 64 + mt * 16 + l15][kk * 32 + lg * 8]);
#pragma unroll
            for (int nt = 0; nt < 4; nt++)
                b[nt] = *reinterpret_cast<const bf16x8*>(&Bl[wc * 64 + nt * 16 + l15][kk * 32 + lg * 8]);
#pragma unroll
            for (int mt = 0; mt < 4; mt++)
#pragma unroll
                for (int nt = 0; nt < 4; nt++)
                    acc[mt][nt] = __builtin_amdgcn_mfma_f32_16x16x32_bf16(a[mt], b[nt], acc[mt][nt], 0, 0, 0);
        }
    }
#pragma unroll
    for (int mt = 0; mt < 4; mt++)
#pragma unroll
        for (int nt = 0; nt < 4; nt++) {
            int n = n0 + wc * 64 + nt * 16 + l15;
            int part = n >> 10;
            int d = n & 1023;
            int h = d >> 6, dd = d & 63;
            ushort* dst = (part == 0) ? q : ((part == 1) ? k : v);
#pragma unroll
            for (int r = 0; r < 4; r++) {
                int m = m0 + wr * 64 + mt * 16 + lg * 4 + r;
                dst[(((size_t)(m >> 11) * HH + h) * CC + (m & 2047)) * DHH + dd] = f2bf(acc[mt][nt][r]);
            }
        }
}

// ---------------- rotate q,k -> qr,kr (bf16, fp32 math) ----------------
__global__ __launch_bounds__(256) void rot_k(const ushort* __restrict__ q, const ushort* __restrict__ k,
                                             const float* __restrict__ ct, const float* __restrict__ st,
                                             ushort* __restrict__ qr, ushort* __restrict__ kr) {
    int id = blockIdx.x * 256 + threadIdx.x;  // 32*2048*8 = 524288 tasks
    int oct = id & 7;
    int c = (id >> 3) & 2047;
    int bh = id >> 14;
    size_t base = ((size_t)bh * CC + c) * DHH + oct * 8;
    bf16x8 q8 = *reinterpret_cast<const bf16x8*>(q + base);
    bf16x8 k8 = *reinterpret_cast<const bf16x8*>(k + base);
    float4 c4 = *reinterpret_cast<const float4*>(ct + c * 32 + oct * 4);
    float4 s4 = *reinterpret_cast<const float4*>(st + c * 32 + oct * 4);
    float cc[4] = {c4.x, c4.y, c4.z, c4.w};
    float ss[4] = {s4.x, s4.y, s4.z, s4.w};
    bf16x8 qo, ko;
#pragma unroll
    for (int p = 0; p < 4; p++) {
        float qe = bf2f((ushort)q8[2 * p]), qd = bf2f((ushort)q8[2 * p + 1]);
        float ke = bf2f((ushort)k8[2 * p]), kd = bf2f((ushort)k8[2 * p + 1]);
        qo[2 * p]     = (short)f2bf(qe * cc[p] + qd * ss[p]);
        qo[2 * p + 1] = (short)f2bf(qd * cc[p] - qe * ss[p]);
        ko[2 * p]     = (short)f2bf(ke * cc[p] + kd * ss[p]);
        ko[2 * p + 1] = (short)f2bf(kd * cc[p] - ke * ss[p]);
    }
    *reinterpret_cast<bf16x8*>(qr + base) = qo;
    *reinterpret_cast<bf16x8*>(kr + base) = ko;
}

// ---------------- fused attention (bf16 MFMA) ----------------
// Block: 128 queries of one (b,h); 4 waves x 32 rows. K-tiles of 64.
// den = sum over ALL keys exp(q.k/8) (unrotated, no mask); num = exp(qr.kr/8) causal; y = P.V/den
__global__ __launch_bounds__(256) void attn_mfma_k(const ushort* __restrict__ qg,
                                                   const ushort* __restrict__ kg,
                                                   const ushort* __restrict__ vg,
                                                   const ushort* __restrict__ qrg,
                                                   const ushort* __restrict__ krg,
                                                   ushort* __restrict__ y) {
    __shared__ ushort Kl[64][72];
    __shared__ ushort Krl[64][72];
    __shared__ ushort Vt[64][72];       // [d][key]
    __shared__ ushort Pl[4][32][72];    // per-wave P [qrow][key]

    const int tid = threadIdx.x;
    const int w = tid >> 6, l = tid & 63;
    const int l15 = l & 15, lg = l >> 4;
    const int bh = blockIdx.y;
    const int q0 = blockIdx.x * 128;
    const ushort* qb  = qg  + (size_t)bh * CC * DHH;
    const ushort* kb  = kg  + (size_t)bh * CC * DHH;
    const ushort* vb  = vg  + (size_t)bh * CC * DHH;
    const ushort* qrb = qrg + (size_t)bh * CC * DHH;
    const ushort* krb = krg + (size_t)bh * CC * DHH;

    // Q fragments in registers (A-operand layout: row = l15, k = lg*8+i)
    bf16x8 qf[2][2], qrf[2][2];
#pragma unroll
    for (int mt = 0; mt < 2; mt++)
#pragma unroll
        for (int kk = 0; kk < 2; kk++) {
            int row = q0 + w * 32 + mt * 16 + l15;
            qf[mt][kk]  = *reinterpret_cast<const bf16x8*>(qb  + (size_t)row * DHH + kk * 32 + lg * 8);
            qrf[mt][kk] = *reinterpret_cast<const bf16x8*>(qrb + (size_t)row * DHH + kk * 32 + lg * 8);
        }

    f32x4 yacc[2][4];
    float dacc[2][4];
#pragma unroll
    for (int mt = 0; mt < 2; mt++) {
#pragma unroll
        for (int nt = 0; nt < 4; nt++) yacc[mt][nt] = (f32x4){0.f, 0.f, 0.f, 0.f};
#pragma unroll
        for (int r = 0; r < 4; r++) dacc[mt][r] = 0.f;
    }

    for (int kt = 0; kt < CC / 64; kt++) {
        const int k0 = kt * 64;
        const bool need = (k0 <= q0 + 127);
        __syncthreads();
        // stage K (and Kr if needed): 512 tasks (key, oct)
#pragma unroll
        for (int rep = 0; rep < 2; rep++) {
            int id = rep * 256 + tid;
            int key = id >> 3, oct = id & 7;
            *reinterpret_cast<bf16x8*>(&Kl[key][oct * 8]) =
                *reinterpret_cast<const bf16x8*>(kb + (size_t)(k0 + key) * DHH + oct * 8);
            if (need)
                *reinterpret_cast<bf16x8*>(&Krl[key][oct * 8]) =
                    *reinterpret_cast<const bf16x8*>(krb + (size_t)(k0 + key) * DHH + oct * 8);
        }
        // stage V transposed: task (d, oct): read V[k0+oct*8+j][d], write Vt[d][oct*8+j]
        if (need) {
#pragma unroll
            for (int rep = 0; rep < 2; rep++) {
                int id = rep * 256 + tid;
                int d = id & 63, oct = id >> 6;
                bf16x8 tv;
#pragma unroll
                for (int j = 0; j < 8; j++)
                    tv[j] = (short)vb[(size_t)(k0 + oct * 8 + j) * DHH + d];
                *reinterpret_cast<bf16x8*>(&Vt[d][oct * 8]) = tv;
            }
        }
        __syncthreads();

        // denominator: unrotated, all keys
#pragma unroll
        for (int mt = 0; mt < 2; mt++)
#pragma unroll
            for (int nt = 0; nt < 4; nt++) {
                f32x4 s = (f32x4){0.f, 0.f, 0.f, 0.f};
#pragma unroll
                for (int kk = 0; kk < 2; kk++) {
                    bf16x8 bk = *reinterpret_cast<const bf16x8*>(&Kl[nt * 16 + l15][kk * 32 + lg * 8]);
                    s = __builtin_amdgcn_mfma_f32_16x16x32_bf16(qf[mt][kk], bk, s, 0, 0, 0);
                }
#pragma unroll
                for (int r = 0; r < 4; r++) dacc[mt][r] += __expf(s[r] * 0.125f);
            }

        if (need) {
            // numerator: rotated, causal mask, P -> per-wave LDS (bf16)
#pragma unroll
            for (int mt = 0; mt < 2; mt++)
#pragma unroll
                for (int nt = 0; nt < 4; nt++) {
                    f32x4 s = (f32x4){0.f, 0.f, 0.f, 0.f};
#pragma unroll
                    for (int kk = 0; kk < 2; kk++) {
                        bf16x8 bk = *reinterpret_cast<const bf16x8*>(&Krl[nt * 16 + l15][kk * 32 + lg * 8]);
                        s = __builtin_amdgcn_mfma_f32_16x16x32_bf16(qrf[mt][kk], bk, s, 0, 0, 0);
                    }
#pragma unroll
                    for (int r = 0; r < 4; r++) {
                        int qrow = q0 + w * 32 + mt * 16 + lg * 4 + r;
                        int key = k0 + nt * 16 + l15;
                        float p = (key <= qrow) ? __expf(s[r] * 0.125f) : 0.f;
                        Pl[w][mt * 16 + lg * 4 + r][nt * 16 + l15] = f2bf(p);
                    }
                }
            // PV: A = P (per-wave), B = Vt
#pragma unroll
            for (int mt = 0; mt < 2; mt++) {
                bf16x8 pa[2];
#pragma unroll
                for (int kk2 = 0; kk2 < 2; kk2++)
                    pa[kk2] = *reinterpret_cast<const bf16x8*>(&Pl[w][mt * 16 + l15][kk2 * 32 + lg * 8]);
#pragma unroll
                for (int nt2 = 0; nt2 < 4; nt2++)
#pragma unroll
                    for (int kk2 = 0; kk2 < 2; kk2++) {
                        bf16x8 bv = *reinterpret_cast<const bf16x8*>(&Vt[nt2 * 16 + l15][kk2 * 32 + lg * 8]);
                        yacc[mt][nt2] = __builtin_amdgcn_mfma_f32_16x16x32_bf16(pa[kk2], bv, yacc[mt][nt2], 0, 0, 0);
                    }
            }
        }
    }

    // reduce den across the 16 column-lanes (bits 0-3 of lane id)
#pragma unroll
    for (int mt = 0; mt < 2; mt++)
#pragma unroll
        for (int r = 0; r < 4; r++) {
            float vsum = dacc[mt][r];
#pragma unroll
            for (int msk = 1; msk < 16; msk <<= 1) vsum += __shfl_xor(vsum, msk, 64);
            dacc[mt][r] = vsum;
        }

    const int b = bh >> 4, h = bh & 15;
#pragma unroll
    for (int mt = 0; mt < 2; mt++)
#pragma unroll
        for (int r = 0; r < 4; r++) {
            int row = q0 + w * 32 + mt * 16 + lg * 4 + r;
            float inv = 1.f / dacc[mt][r];
#pragma unroll
            for (int nt2 = 0; nt2 < 4; nt2++) {
                int d = nt2 * 16 + l15;
                y[((size_t)b * CC + row) * DD + h * DHH + d] = f2bf(yacc[mt][nt2][r] * inv);
            }
        }
}

// ---------------- output projection (bf16 MFMA, fp32 out + bias) ----------------
__global__ __launch_bounds__(256) void out_proj_mfma_k(const ushort* __restrict__ yb,
                                                       const ushort* __restrict__ wob,
                                                       const float* __restrict__ bias,
                                                       float* __restrict__ out) {
    __shared__ ushort Al[128][72];
    __shared__ ushort Bl[128][72];
    const int tid = threadIdx.x;
    const int w = tid >> 6, l = tid & 63;
    const int l15 = l & 15, lg = l >> 4;
    const int wr = w >> 1, wc = w & 1;
    const int m0 = blockIdx.x * 128, n0 = blockIdx.y * 128;

    f32x4 acc[4][4];
#pragma unroll
    for (int i = 0; i < 4; i++)
#pragma unroll
        for (int j = 0; j < 4; j++) acc[i][j] = (f32x4){0.f, 0.f, 0.f, 0.f};

    for (int k0 = 0; k0 < 1024; k0 += 64) {
        __syncthreads();
#pragma unroll
        for (int rep = 0; rep < 4; rep++) {
            int id = rep * 256 + tid;
            int row = id >> 3, oct = id & 7;
            *reinterpret_cast<bf16x8*>(&Al[row][oct * 8]) =
                *reinterpret_cast<const bf16x8*>(yb + (size_t)(m0 + row) * 1024 + k0 + oct * 8);
            *reinterpret_cast<bf16x8*>(&Bl[row][oct * 8]) =
                *reinterpret_cast<const bf16x8*>(wob + (size_t)(n0 + row) * 1024 + k0 + oct * 8);
        }
        __syncthreads();
#pragma unroll
        for (int kk = 0; kk < 2; kk++) {
            bf16x8 a[4], b[4];
#pragma unroll
            for (int mt = 0; mt < 4; mt++)
                a[mt] = *reinterpret_cast<const bf16x8*>(&Al[wr * 64 + mt * 16 + l15][kk * 32 + lg * 8]);
#pragma unroll
            for (int nt = 0; nt < 4; nt++)
                b[nt] = *reinterpret_cast<const bf16x8*>(&Bl[wc * 64 + nt * 16 + l15][kk * 32 + lg * 8]);
#pragma unroll
            for (int mt = 0; mt < 4; mt++)
#pragma unroll
                for (int nt = 0; nt < 4; nt++)
                    acc[mt][nt] = __builtin_amdgcn_mfma_f32_16x16x32_bf16(a[mt], b[nt], acc[mt][nt], 0, 0, 0);
        }
    }
#pragma unroll
    for (int mt = 0; mt < 4; mt++)
#pragma unroll
        for (int nt = 0; nt < 4; nt++) {
            int n = n0 + wc * 64 + nt * 16 + l15;
            float bv = bias[n];
#pragma unroll
            for (int r = 0; r < 4; r++) {
                int m = m0 + wr * 64 + mt * 16 + lg * 4 + r;
                out[(size_t)m * 1024 + n] = acc[mt][nt][r] + bv;
            }
        }
}

extern "C" void kernel_launch(void* const* d_in, const int* in_sizes, int n_in,
                              void* d_out, int out_size, void* d_ws, size_t ws_size,
                              hipStream_t stream) {
    (void)in_sizes; (void)n_in; (void)out_size; (void)ws_size;
    const float* x     = (const float*)d_in[0];
    const float* w_qkv = (const float*)d_in[1];
    const float* w_out = (const float*)d_in[2];
    const float* b_out = (const float*)d_in[3];
    float* out = (float*)d_out;

    char* p = (char*)d_ws;
    float* ct = (float*)p;  p += (size_t)CC * HALF * 4;
    float* st = (float*)p;  p += (size_t)CC * HALF * 4;
    ushort* xb  = (ushort*)p; p += (size_t)4096 * 1024 * 2;
    ushort* wqb = (ushort*)p; p += (size_t)3072 * 1024 * 2;
    ushort* wob = (ushort*)p; p += (size_t)1024 * 1024 * 2;
    const size_t TEN = (size_t)BB * HH * CC * DHH;  // 4,194,304
    ushort* qb = (ushort*)p; p += TEN * 2;
    ushort* kb = (ushort*)p; p += TEN * 2;
    ushort* vb = (ushort*)p; p += TEN * 2;
    ushort* qr = (ushort*)p; p += TEN * 2;
    ushort* kr = (ushort*)p; p += TEN * 2;
    ushort* yb = (ushort*)p; p += (size_t)4096 * 1024 * 2;

    cast_bf16_k<<<dim3(2048), dim3(256), 0, stream>>>(x, xb, 524288);
    cast_bf16_k<<<dim3(1536), dim3(256), 0, stream>>>(w_qkv, wqb, 393216);
    cast_bf16_k<<<dim3(512),  dim3(256), 0, stream>>>(w_out, wob, 131072);
    rope_table_k<<<dim3((CC * HALF) / 256), dim3(256), 0, stream>>>(ct, st);
    qkv_gemm_mfma_k<<<dim3(32, 24), dim3(256), 0, stream>>>(xb, wqb, qb, kb, vb);
    rot_k<<<dim3(2048), dim3(256), 0, stream>>>(qb, kb, ct, st, qr, kr);
    attn_mfma_k<<<dim3(16, 32), dim3(256), 0, stream>>>(qb, kb, vb, qr, kr, yb);
    out_proj_mfma_k<<<dim3(32, 8), dim3(256), 0, stream>>>(yb, wob, b_out, out);
}

// Round 3
// 179.586 us; speedup vs baseline: 10.0264x; 1.0978x over previous
//
#include <hip/hip_runtime.h>
#include <math.h>
#include <stdint.h>

#define BB 2
#define CC 2048
#define DD 1024
#define HH 16
#define DHH 64
#define HALF 32

typedef __attribute__((ext_vector_type(8))) short bf16x8;
typedef __attribute__((ext_vector_type(4))) float f32x4;
typedef unsigned int u32;

__device__ __forceinline__ ushort f2bf(float f) {
    uint32_t u = __builtin_bit_cast(uint32_t, f);
    u = (u + 0x7FFFu + ((u >> 16) & 1u)) >> 16;
    return (ushort)u;
}
__device__ __forceinline__ float bf2f(ushort u) {
    return __builtin_bit_cast(float, ((uint32_t)u) << 16);
}

// async global->LDS, 16B per lane; LDS dest = base(wave-uniform) + lane*16
__device__ __forceinline__ void gload16(const void* g, void* lds) {
    __builtin_amdgcn_global_load_lds(
        (const u32 __attribute__((address_space(1)))*)g,
        (u32 __attribute__((address_space(3)))*)lds, 16, 0, 0);
}

// ---------------- fp32 -> bf16 cast ----------------
__global__ __launch_bounds__(256) void cast_bf16_k(const float* __restrict__ src,
                                                   ushort* __restrict__ dst, int n8) {
    int id = blockIdx.x * 256 + threadIdx.x;
    if (id >= n8) return;
    float4 a = *reinterpret_cast<const float4*>(src + (size_t)id * 8);
    float4 b = *reinterpret_cast<const float4*>(src + (size_t)id * 8 + 4);
    bf16x8 o;
    o[0] = (short)f2bf(a.x); o[1] = (short)f2bf(a.y);
    o[2] = (short)f2bf(a.z); o[3] = (short)f2bf(a.w);
    o[4] = (short)f2bf(b.x); o[5] = (short)f2bf(b.y);
    o[6] = (short)f2bf(b.z); o[7] = (short)f2bf(b.w);
    *reinterpret_cast<bf16x8*>(dst + (size_t)id * 8) = o;
}

// ---------------- RoPE cos/sin table ----------------
__global__ __launch_bounds__(256) void rope_table_k(float* __restrict__ ct, float* __restrict__ st) {
    int idx = blockIdx.x * 256 + threadIdx.x;
    if (idx >= CC * HALF) return;
    int m = idx >> 5;
    int t = idx & 31;
    double theta_d = pow(10000.0, -2.0 * ((double)t - 1.0) / 64.0);
    float theta = (float)theta_d;
    float ang = (float)m * theta;
    ct[idx] = cosf(ang);
    st[idx] = sinf(ang);
}

// ---------------- QKV GEMM (bf16 MFMA, global_load_lds staging) ----------------
// C[m][n] = sum_k x[m][k]*w[n][k]; q,k row-major [B,H,C,64]; v TRANSPOSED vT[bh][d][c]
__global__ __launch_bounds__(256) void qkv_gemm_mfma_k(const ushort* __restrict__ xb,
                                                       const ushort* __restrict__ wqb,
                                                       ushort* __restrict__ q,
                                                       ushort* __restrict__ k,
                                                       ushort* __restrict__ vT) {
    __shared__ ushort Al[128 * 64];
    __shared__ ushort Bl[128 * 64];
    const int tid = threadIdx.x;
    const int w = tid >> 6, l = tid & 63;
    const int l15 = l & 15, lg = l >> 4;
    const int wr = w >> 1, wc = w & 1;
    const int m0 = blockIdx.x * 128, n0 = blockIdx.y * 128;
    const int lrow = l >> 3, lch = l & 7;

    f32x4 acc[4][4];
#pragma unroll
    for (int i = 0; i < 4; i++)
#pragma unroll
        for (int j = 0; j < 4; j++) acc[i][j] = (f32x4){0.f, 0.f, 0.f, 0.f};

    for (int k0 = 0; k0 < 1024; k0 += 64) {
        __syncthreads();
#pragma unroll
        for (int c = 0; c < 4; c++) {
            int row = w * 32 + c * 8 + lrow;
            int gch = (lch ^ (row & 7)) * 8;
            gload16(xb + (size_t)(m0 + row) * 1024 + k0 + gch, &Al[(w * 32 + c * 8) * 64]);
            gload16(wqb + (size_t)(n0 + row) * 1024 + k0 + gch, &Bl[(w * 32 + c * 8) * 64]);
        }
        __syncthreads();
#pragma unroll
        for (int kk = 0; kk < 2; kk++) {
            bf16x8 a[4], b[4];
#pragma unroll
            for (int mt = 0; mt < 4; mt++) {
                int row = wr * 64 + mt * 16 + l15;
                a[mt] = *reinterpret_cast<const bf16x8*>(&Al[row * 64 + ((kk * 4 + lg) ^ (row & 7)) * 8]);
            }
#pragma unroll
            for (int nt = 0; nt < 4; nt++) {
                int row = wc * 64 + nt * 16 + l15;
                b[nt] = *reinterpret_cast<const bf16x8*>(&Bl[row * 64 + ((kk * 4 + lg) ^ (row & 7)) * 8]);
            }
#pragma unroll
            for (int mt = 0; mt < 4; mt++)
#pragma unroll
                for (int nt = 0; nt < 4; nt++)
                    acc[mt][nt] = __builtin_amdgcn_mfma_f32_16x16x32_bf16(a[mt], b[nt], acc[mt][nt], 0, 0, 0);
        }
    }
#pragma unroll
    for (int mt = 0; mt < 4; mt++)
#pragma unroll
        for (int nt = 0; nt < 4; nt++) {
            int n = n0 + wc * 64 + nt * 16 + l15;
            int part = n >> 10;
            int d = n & 1023;
            int h = d >> 6, dd = d & 63;
            int mbase = m0 + wr * 64 + mt * 16 + lg * 4;
            int bb = mbase >> 11, cpos = mbase & 2047;
            if (part == 2) {
                ushort4 pk;
                pk.x = f2bf(acc[mt][nt][0]); pk.y = f2bf(acc[mt][nt][1]);
                pk.z = f2bf(acc[mt][nt][2]); pk.w = f2bf(acc[mt][nt][3]);
                *reinterpret_cast<ushort4*>(vT + (((size_t)bb * HH + h) * DHH + dd) * CC + cpos) = pk;
            } else {
                ushort* dst = (part == 0) ? q : k;
#pragma unroll
                for (int r = 0; r < 4; r++)
                    dst[(((size_t)bb * HH + h) * CC + (cpos + r)) * DHH + dd] = f2bf(acc[mt][nt][r]);
            }
        }
}

// ---------------- rotate q,k -> qr,kr ----------------
__global__ __launch_bounds__(256) void rot_k(const ushort* __restrict__ q, const ushort* __restrict__ k,
                                             const float* __restrict__ ct, const float* __restrict__ st,
                                             ushort* __restrict__ qr, ushort* __restrict__ kr) {
    int id = blockIdx.x * 256 + threadIdx.x;
    int oct = id & 7;
    int c = (id >> 3) & 2047;
    int bh = id >> 14;
    size_t base = ((size_t)bh * CC + c) * DHH + oct * 8;
    bf16x8 q8 = *reinterpret_cast<const bf16x8*>(q + base);
    bf16x8 k8 = *reinterpret_cast<const bf16x8*>(k + base);
    float4 c4 = *reinterpret_cast<const float4*>(ct + c * 32 + oct * 4);
    float4 s4 = *reinterpret_cast<const float4*>(st + c * 32 + oct * 4);
    float cc[4] = {c4.x, c4.y, c4.z, c4.w};
    float ss[4] = {s4.x, s4.y, s4.z, s4.w};
    bf16x8 qo, ko;
#pragma unroll
    for (int p = 0; p < 4; p++) {
        float qe = bf2f((ushort)q8[2 * p]), qd = bf2f((ushort)q8[2 * p + 1]);
        float ke = bf2f((ushort)k8[2 * p]), kd = bf2f((ushort)k8[2 * p + 1]);
        qo[2 * p]     = (short)f2bf(qe * cc[p] + qd * ss[p]);
        qo[2 * p + 1] = (short)f2bf(qd * cc[p] - qe * ss[p]);
        ko[2 * p]     = (short)f2bf(ke * cc[p] + kd * ss[p]);
        ko[2 * p + 1] = (short)f2bf(kd * cc[p] - ke * ss[p]);
    }
    *reinterpret_cast<bf16x8*>(qr + base) = qo;
    *reinterpret_cast<bf16x8*>(kr + base) = ko;
}

// ---------------- fused attention ----------------
// Block = 64 queries of one (b,h); 4 waves x 16 rows. grid 1024 (balanced tile remap).
#define PSTR 76
__global__ __launch_bounds__(256) void attn_mfma_k(const ushort* __restrict__ qg,
                                                   const ushort* __restrict__ kg,
                                                   const ushort* __restrict__ vTg,
                                                   const ushort* __restrict__ qrg,
                                                   const ushort* __restrict__ krg,
                                                   ushort* __restrict__ y) {
    __shared__ ushort Kl[64 * 64];
    __shared__ ushort Krl[64 * 64];
    __shared__ ushort Vt[64 * 64];
    __shared__ ushort Pl[4][16 * PSTR];

    const int tid = threadIdx.x;
    const int w = tid >> 6, l = tid & 63;
    const int l15 = l & 15, lg = l >> 4;
    const int lrow = l >> 3, lch = l & 7;
    const int bid = blockIdx.x;
    const int bh = bid >> 5;
    const int xt = bid & 31;
    const int tile = (bid & 512) ? (31 - xt) : xt;
    const int q0 = tile * 64;
    const ushort* qb  = qg  + (size_t)bh * CC * DHH;
    const ushort* kb  = kg  + (size_t)bh * CC * DHH;
    const ushort* vTb = vTg + (size_t)bh * DHH * CC;
    const ushort* qrb = qrg + (size_t)bh * CC * DHH;
    const ushort* krb = krg + (size_t)bh * CC * DHH;

    // Q fragments (A-operand: row=l15, k=lg*8+i), wave owns rows q0+w*16..+15
    bf16x8 qf[2], qrf[2];
#pragma unroll
    for (int kk = 0; kk < 2; kk++) {
        int row = q0 + w * 16 + l15;
        qf[kk]  = *reinterpret_cast<const bf16x8*>(qb  + (size_t)row * DHH + kk * 32 + lg * 8);
        qrf[kk] = *reinterpret_cast<const bf16x8*>(qrb + (size_t)row * DHH + kk * 32 + lg * 8);
    }

    f32x4 yacc[4];
    float dacc[4];
#pragma unroll
    for (int nt = 0; nt < 4; nt++) yacc[nt] = (f32x4){0.f, 0.f, 0.f, 0.f};
#pragma unroll
    for (int r = 0; r < 4; r++) dacc[r] = 0.f;

    for (int kt = 0; kt < CC / 64; kt++) {
        const int k0 = kt * 64;
        const bool need = (k0 <= q0 + 63);
        __syncthreads();
        // stage K (always), Kr+Vt (causal tiles) via global_load_lds, swizzled source
#pragma unroll
        for (int c = 0; c < 2; c++) {
            int row = w * 16 + c * 8 + lrow;
            int gch = (lch ^ (row & 7)) * 8;
            gload16(kb + (size_t)(k0 + row) * DHH + gch, &Kl[(w * 16 + c * 8) * 64]);
            if (need) {
                gload16(krb + (size_t)(k0 + row) * DHH + gch, &Krl[(w * 16 + c * 8) * 64]);
                gload16(vTb + (size_t)row * CC + k0 + gch, &Vt[(w * 16 + c * 8) * 64]);
            }
        }
        __syncthreads();

        // denominator: unrotated, all keys
#pragma unroll
        for (int nt = 0; nt < 4; nt++) {
            f32x4 s = (f32x4){0.f, 0.f, 0.f, 0.f};
#pragma unroll
            for (int kk = 0; kk < 2; kk++) {
                int row = nt * 16 + l15;
                bf16x8 bk = *reinterpret_cast<const bf16x8*>(&Kl[row * 64 + ((kk * 4 + lg) ^ (row & 7)) * 8]);
                s = __builtin_amdgcn_mfma_f32_16x16x32_bf16(qf[kk], bk, s, 0, 0, 0);
            }
#pragma unroll
            for (int r = 0; r < 4; r++) dacc[r] += exp2f(s[r] * 0.1803368801f);
        }

        if (need) {
            // numerator: rotated, causal mask, P -> per-wave LDS
#pragma unroll
            for (int nt = 0; nt < 4; nt++) {
                f32x4 s = (f32x4){0.f, 0.f, 0.f, 0.f};
#pragma unroll
                for (int kk = 0; kk < 2; kk++) {
                    int row = nt * 16 + l15;
                    bf16x8 bk = *reinterpret_cast<const bf16x8*>(&Krl[row * 64 + ((kk * 4 + lg) ^ (row & 7)) * 8]);
                    s = __builtin_amdgcn_mfma_f32_16x16x32_bf16(qrf[kk], bk, s, 0, 0, 0);
                }
#pragma unroll
                for (int r = 0; r < 4; r++) {
                    int qrow = q0 + w * 16 + lg * 4 + r;
                    int key = k0 + nt * 16 + l15;
                    float p = (key <= qrow) ? exp2f(s[r] * 0.1803368801f) : 0.f;
                    Pl[w][(lg * 4 + r) * PSTR + nt * 16 + l15] = f2bf(p);
                }
            }
            // PV: A = P (per-wave), B = Vt
            bf16x8 pa[2];
#pragma unroll
            for (int kk2 = 0; kk2 < 2; kk2++)
                pa[kk2] = *reinterpret_cast<const bf16x8*>(&Pl[w][l15 * PSTR + kk2 * 32 + lg * 8]);
#pragma unroll
            for (int nt2 = 0; nt2 < 4; nt2++)
#pragma unroll
                for (int kk2 = 0; kk2 < 2; kk2++) {
                    int row = nt2 * 16 + l15;
                    bf16x8 bv = *reinterpret_cast<const bf16x8*>(&Vt[row * 64 + ((kk2 * 4 + lg) ^ (row & 7)) * 8]);
                    yacc[nt2] = __builtin_amdgcn_mfma_f32_16x16x32_bf16(pa[kk2], bv, yacc[nt2], 0, 0, 0);
                }
        }
    }

    // reduce den across the 16 column-lanes
#pragma unroll
    for (int r = 0; r < 4; r++) {
        float vsum = dacc[r];
#pragma unroll
        for (int msk = 1; msk < 16; msk <<= 1) vsum += __shfl_xor(vsum, msk, 64);
        dacc[r] = vsum;
    }

    const int b = bh >> 4, h = bh & 15;
#pragma unroll
    for (int r = 0; r < 4; r++) {
        int row = q0 + w * 16 + lg * 4 + r;
        float inv = 1.f / dacc[r];
#pragma unroll
        for (int nt2 = 0; nt2 < 4; nt2++) {
            int d = nt2 * 16 + l15;
            y[((size_t)b * CC + row) * DD + h * DHH + d] = f2bf(yacc[nt2][r] * inv);
        }
    }
}

// ---------------- output projection ----------------
__global__ __launch_bounds__(256) void out_proj_mfma_k(const ushort* __restrict__ yb,
                                                       const ushort* __restrict__ wob,
                                                       const float* __restrict__ bias,
                                                       float* __restrict__ out) {
    __shared__ ushort Al[128 * 64];
    __shared__ ushort Bl[128 * 64];
    const int tid = threadIdx.x;
    const int w = tid >> 6, l = tid & 63;
    const int l15 = l & 15, lg = l >> 4;
    const int wr = w >> 1, wc = w & 1;
    const int m0 = blockIdx.x * 128, n0 = blockIdx.y * 128;
    const int lrow = l >> 3, lch = l & 7;

    f32x4 acc[4][4];
#pragma unroll
    for (int i = 0; i < 4; i++)
#pragma unroll
        for (int j = 0; j < 4; j++) acc[i][j] = (f32x4){0.f, 0.f, 0.f, 0.f};

    for (int k0 = 0; k0 < 1024; k0 += 64) {
        __syncthreads();
#pragma unroll
        for (int c = 0; c < 4; c++) {
            int row = w * 32 + c * 8 + lrow;
            int gch = (lch ^ (row & 7)) * 8;
            gload16(yb + (size_t)(m0 + row) * 1024 + k0 + gch, &Al[(w * 32 + c * 8) * 64]);
            gload16(wob + (size_t)(n0 + row) * 1024 + k0 + gch, &Bl[(w * 32 + c * 8) * 64]);
        }
        __syncthreads();
#pragma unroll
        for (int kk = 0; kk < 2; kk++) {
            bf16x8 a[4], b[4];
#pragma unroll
            for (int mt = 0; mt < 4; mt++) {
                int row = wr * 64 + mt * 16 + l15;
                a[mt] = *reinterpret_cast<const bf16x8*>(&Al[row * 64 + ((kk * 4 + lg) ^ (row & 7)) * 8]);
            }
#pragma unroll
            for (int nt = 0; nt < 4; nt++) {
                int row = wc * 64 + nt * 16 + l15;
                b[nt] = *reinterpret_cast<const bf16x8*>(&Bl[row * 64 + ((kk * 4 + lg) ^ (row & 7)) * 8]);
            }
#pragma unroll
            for (int mt = 0; mt < 4; mt++)
#pragma unroll
                for (int nt = 0; nt < 4; nt++)
                    acc[mt][nt] = __builtin_amdgcn_mfma_f32_16x16x32_bf16(a[mt], b[nt], acc[mt][nt], 0, 0, 0);
        }
    }
#pragma unroll
    for (int mt = 0; mt < 4; mt++)
#pragma unroll
        for (int nt = 0; nt < 4; nt++) {
            int n = n0 + wc * 64 + nt * 16 + l15;
            float bv = bias[n];
#pragma unroll
            for (int r = 0; r < 4; r++) {
                int m = m0 + wr * 64 + mt * 16 + lg * 4 + r;
                out[(size_t)m * 1024 + n] = acc[mt][nt][r] + bv;
            }
        }
}

extern "C" void kernel_launch(void* const* d_in, const int* in_sizes, int n_in,
                              void* d_out, int out_size, void* d_ws, size_t ws_size,
                              hipStream_t stream) {
    (void)in_sizes; (void)n_in; (void)out_size; (void)ws_size;
    const float* x     = (const float*)d_in[0];
    const float* w_qkv = (const float*)d_in[1];
    const float* w_out = (const float*)d_in[2];
    const float* b_out = (const float*)d_in[3];
    float* out = (float*)d_out;

    char* p = (char*)d_ws;
    float* ct = (float*)p;  p += (size_t)CC * HALF * 4;
    float* st = (float*)p;  p += (size_t)CC * HALF * 4;
    ushort* xb  = (ushort*)p; p += (size_t)4096 * 1024 * 2;
    ushort* wqb = (ushort*)p; p += (size_t)3072 * 1024 * 2;
    ushort* wob = (ushort*)p; p += (size_t)1024 * 1024 * 2;
    const size_t TEN = (size_t)BB * HH * CC * DHH;  // 4,194,304
    ushort* qb = (ushort*)p; p += TEN * 2;
    ushort* kb = (ushort*)p; p += TEN * 2;
    ushort* vT = (ushort*)p; p += TEN * 2;
    ushort* qr = (ushort*)p; p += TEN * 2;
    ushort* kr = (ushort*)p; p += TEN * 2;
    ushort* yb = (ushort*)p; p += (size_t)4096 * 1024 * 2;

    cast_bf16_k<<<dim3(2048), dim3(256), 0, stream>>>(x, xb, 524288);
    cast_bf16_k<<<dim3(1536), dim3(256), 0, stream>>>(w_qkv, wqb, 393216);
    cast_bf16_k<<<dim3(512),  dim3(256), 0, stream>>>(w_out, wob, 131072);
    rope_table_k<<<dim3((CC * HALF) / 256), dim3(256), 0, stream>>>(ct, st);
    qkv_gemm_mfma_k<<<dim3(32, 24), dim3(256), 0, stream>>>(xb, wqb, qb, kb, vT);
    rot_k<<<dim3(2048), dim3(256), 0, stream>>>(qb, kb, ct, st, qr, kr);
    attn_mfma_k<<<dim3(1024), dim3(256), 0, stream>>>(qb, kb, vT, qr, kr, yb);
    out_proj_mfma_k<<<dim3(32, 8), dim3(256), 0, stream>>>(yb, wob, b_out, out);
}